// Round 14
// baseline (371.090 us; speedup 1.0000x reference)
//
#include <hip/hip_runtime.h>
#include <math.h>

#define N_NODES 100000
#define N_EDGESI 1600000
#define E_TOTAL (N_EDGESI + N_NODES)
#define N_GRAPHS 2000
#define F_IN 16
#define HEADS 8
#define CPH 16
#define HC 128
#define NEG 0.2f
#define SCAN_B 1024
#define NB_SCAN ((N_NODES + SCAN_B - 1)/SCAN_B)   // 98

// bucketed scatter params
#define BSHIFT 9
#define BNODES (1<<BSHIFT)                         // 512 nodes per bucket
#define NBUK ((N_NODES + BNODES - 1)/BNODES)       // 196
#define BCAP 12288
#define BIN_EPT 32
#define BIN_TPB 256
#define BIN_EPB (BIN_EPT*BIN_TPB)                  // 8192
#define NBIN_BLK ((E_TOTAL + BIN_EPB - 1)/BIN_EPB) // 208
#define CSR_SPLIT 8

#define GOFF_BLK ((N_NODES+255)/256)               // 391
#define WCONV_BLK ((HC*HC)/256)                    // 64
#define XCONV_BLK ((N_NODES*4 + 255)/256)          // 1563
#define W1CONV_BLK ((HC*32)/256)                   // 16

typedef __bf16 bf16x8 __attribute__((ext_vector_type(8)));
typedef float  f32x4  __attribute__((ext_vector_type(4)));

__device__ __forceinline__ float leaky(float x){ return fmaxf(x, NEG*x); }
__device__ __forceinline__ float bf2f(unsigned short u){ return __uint_as_float(((unsigned)u)<<16); }
__device__ __forceinline__ unsigned short f2bf(float f){
  unsigned u = __float_as_uint(f);
  unsigned r = (u + 0x7fffu + ((u>>16)&1u)) >> 16;
  return (unsigned short)r;
}
__device__ __forceinline__ float blo(unsigned u){ return __uint_as_float(u<<16); }
__device__ __forceinline__ float bhi(unsigned u){ return __uint_as_float(u & 0xffff0000u); }

// ---------- K1: bin (2-pass) + per-node counts | goff | W2t | x->bf16 | W1t ----------
__global__ void k_pre(const int* __restrict__ ei, int* __restrict__ gpos, unsigned* __restrict__ gbin,
                      int* __restrict__ cnt_g,
                      const int* __restrict__ batch, int* __restrict__ goff,
                      const float* __restrict__ W2, unsigned short* __restrict__ w2t,
                      const float* __restrict__ x, unsigned short* __restrict__ xbf,
                      const float* __restrict__ W1, unsigned short* __restrict__ w1t){
  int blk = blockIdx.x;
  if (blk < NBIN_BLK){
    __shared__ int cnt[NBUK];     // pass-A bucket counts
    __shared__ int rnk[NBUK];     // pass-B rank cursors
    __shared__ int bbase[NBUK];   // global base per bucket for this block
    int t = threadIdx.x;
    for (int i = t; i < NBUK; i += BIN_TPB){ cnt[i] = 0; rnk[i] = 0; }
    __syncthreads();
    int base = blk*BIN_EPB;
    // pass A: bucket counts + global per-node counts
    #pragma unroll 4
    for (int i = 0; i < BIN_EPT; ++i){
      int e = base + i*BIN_TPB + t;
      if (e < E_TOTAL){
        unsigned d = (e < N_EDGESI) ? (unsigned)ei[N_EDGESI + e] : (unsigned)(e - N_EDGESI);
        atomicAdd(&cnt[d >> BSHIFT], 1);
        atomicAdd(&cnt_g[d], 1);
      }
    }
    __syncthreads();
    for (int i = t; i < NBUK; i += BIN_TPB){
      int v = cnt[i];
      bbase[i] = v ? atomicAdd(&gpos[i], v) : 0;
    }
    __syncthreads();
    // pass B: re-read, rank, ranked write (segments L2-absorbed)
    #pragma unroll 4
    for (int i = 0; i < BIN_EPT; ++i){
      int e = base + i*BIN_TPB + t;
      if (e < E_TOTAL){
        unsigned s, d;
        if (e < N_EDGESI){ s = (unsigned)ei[e]; d = (unsigned)ei[N_EDGESI + e]; }
        else { s = d = (unsigned)(e - N_EDGESI); }
        int b = (int)(d >> BSHIFT);
        int r = atomicAdd(&rnk[b], 1);
        gbin[(size_t)b*BCAP + bbase[b] + r] = ((d & (BNODES-1u)) << 17) | s;
      }
    }
  } else if (blk < NBIN_BLK + GOFF_BLK){
    int n = (blk - NBIN_BLK)*256 + threadIdx.x;
    if (n >= N_NODES) return;
    int b = batch[n];
    if (n == 0){ for (int g = 0; g <= b; ++g) goff[g] = 0; }
    int b1 = (n+1 < N_NODES) ? batch[n+1] : N_GRAPHS;
    for (int g = b+1; g <= b1; ++g) goff[g] = n+1;
  } else if (blk < NBIN_BLK + GOFF_BLK + WCONV_BLK){
    int i = (blk - NBIN_BLK - GOFF_BLK)*256 + threadIdx.x;  // c*128 + k
    if (i >= HC*HC) return;
    int c = i >> 7, k = i & 127;
    w2t[i] = f2bf(W2[k*HC + c]);
  } else if (blk < NBIN_BLK + GOFF_BLK + WCONV_BLK + XCONV_BLK){
    int p = (blk - NBIN_BLK - GOFF_BLK - WCONV_BLK)*256 + threadIdx.x;  // n*4 + quad
    if (p >= N_NODES*4) return;
    int n = p >> 2, q = p & 3;
    float4 xv = ((const float4*)(x + n*F_IN))[q];
    ushort4 o; o.x = f2bf(xv.x); o.y = f2bf(xv.y); o.z = f2bf(xv.z); o.w = f2bf(xv.w);
    ((ushort4*)(xbf + (size_t)n*32))[q] = o;
    ushort4 z; z.x = 0; z.y = 0; z.z = 0; z.w = 0;
    ((ushort4*)(xbf + (size_t)n*32 + 16))[q] = z;
  } else {
    int i = (blk - NBIN_BLK - GOFF_BLK - WCONV_BLK - XCONV_BLK)*256 + threadIdx.x;  // c*32+k
    if (i >= HC*32) return;
    int c = i >> 5, k = i & 31;
    w1t[i] = (k < F_IN) ? f2bf(W1[k*HC + c]) : (unsigned short)0;
  }
}

// ---------- scan (verified round-2 kernels) ----------
__global__ void k_scan1(const int* __restrict__ cnt, int* __restrict__ off, int* __restrict__ bsum){
  __shared__ int ws[16];
  int b = blockIdx.x, t = threadIdx.x, lane = t & 63, wv = t >> 6;
  int i = b*SCAN_B + t;
  int v = (i < N_NODES) ? cnt[i] : 0;
  int sc = v;
  #pragma unroll
  for (int o=1;o<64;o<<=1){ int u = __shfl_up(sc, o, 64); if (lane >= o) sc += u; }
  if (lane==63) ws[wv] = sc;
  __syncthreads();
  if (wv==0 && lane<16){
    int w = ws[lane];
    #pragma unroll
    for (int o=1;o<16;o<<=1){ int u = __shfl_up(w,o,64); if (lane>=o) w += u; }
    ws[lane] = w;
  }
  __syncthreads();
  int base = wv ? ws[wv-1] : 0;
  if (i < N_NODES) off[i] = base + sc - v;
  if (t == SCAN_B-1) bsum[b] = ws[15];
}

__global__ void k_scan2(int* __restrict__ bsum, int nb){
  __shared__ int ws[4];
  int t = threadIdx.x, lane = t & 63, wv = t >> 6;
  int v = (t < nb) ? bsum[t] : 0;
  int sc = v;
  #pragma unroll
  for (int o=1;o<64;o<<=1){ int u = __shfl_up(sc,o,64); if (lane>=o) sc += u; }
  if (lane==63) ws[wv] = sc;
  __syncthreads();
  if (wv==0 && lane<4){
    int w = ws[lane];
    #pragma unroll
    for (int o=1;o<4;o<<=1){ int u = __shfl_up(w,o,64); if (lane>=o) w += u; }
    ws[lane] = w;
  }
  __syncthreads();
  int base = wv ? ws[wv-1] : 0;
  int excl = base + sc - v;
  int total = ws[3];
  __syncthreads();
  if (t < nb) bsum[t] = excl;
  if (t == nb) bsum[nb] = total;
}

__global__ void k_scan3(int* __restrict__ off, const int* __restrict__ bsum, int* __restrict__ cur){
  int i = blockIdx.x*256 + threadIdx.x;
  if (i < N_NODES){
    int v = off[i] + bsum[i>>10];
    off[i] = v; cur[i] = v;
  }
  if (i == 0) off[N_NODES] = bsum[NB_SCAN];
}

// ---------- scatter-only CSR finalize: 8 sub-blocks per bucket, global cursors ----------
__global__ void k_csrs(const int* __restrict__ gpos, const unsigned* __restrict__ gbin,
                       int* __restrict__ cur, int* __restrict__ csrc){
  int b = blockIdx.x / CSR_SPLIT, part = blockIdx.x % CSR_SPLIT;
  int nb = gpos[b];
  int lo = (int)(((long long)nb*part)/CSR_SPLIT);
  int hi = (int)(((long long)nb*(part+1))/CSR_SPLIT);
  const unsigned* bb = gbin + (size_t)b*BCAP;
  int d0 = b << BSHIFT;
  for (int i = lo + threadIdx.x; i < hi; i += 256){
    unsigned en = bb[i];
    int p = atomicAdd(&cur[d0 + (int)(en >> 17)], 1);
    csrc[p] = (int)(en & 0x1ffffu);
  }
}

// ---------- GEMM via MFMA bf16 (both layers), fused logits via LDS stage ----------
template<int KS>
__global__ __launch_bounds__(256) void k_gemm_mfma(
                             const unsigned short* __restrict__ hin,
                             const unsigned short* __restrict__ wt,
                             const float* __restrict__ asrc, const float* __restrict__ adst,
                             unsigned short* __restrict__ hb,
                             float* __restrict__ ls, float* __restrict__ ld){
  __shared__ unsigned short hls[64][132];   // pad 132 -> conflict-free b64 reads
  const int KST = KS*32;
  int t = threadIdx.x, lane = t & 63, wv = t >> 6;
  int n0 = blockIdx.x*64 + wv*16;
  int rowl = lane & 15, kgrp = lane >> 4;
  int row = n0 + rowl;
  int rowc = (row < N_NODES) ? row : (N_NODES-1);
  bf16x8 a[KS];
  #pragma unroll
  for (int ks = 0; ks < KS; ++ks)
    a[ks] = *(const bf16x8*)(hin + (size_t)rowc*KST + ks*32 + kgrp*8);
  #pragma unroll
  for (int ct = 0; ct < 8; ++ct){
    f32x4 acc = {0.f, 0.f, 0.f, 0.f};
    int col = ct*16 + rowl;
    #pragma unroll
    for (int ks = 0; ks < KS; ++ks){
      bf16x8 b = *(const bf16x8*)(wt + (size_t)col*KST + ks*32 + kgrp*8);
      acc = __builtin_amdgcn_mfma_f32_16x16x32_bf16(a[ks], b, acc, 0, 0, 0);
    }
    #pragma unroll
    for (int r = 0; r < 4; ++r){
      int lrow = wv*16 + kgrp*4 + r;
      int ro = n0 + kgrp*4 + r;
      unsigned short hv = f2bf(acc[r]);
      hls[lrow][col] = hv;
      if (ro < N_NODES) hb[(size_t)ro*HC + col] = hv;
    }
  }
  __syncthreads();
  // logits: 512 (row,head) pairs over 256 threads
  #pragma unroll
  for (int pp = 0; pp < 2; ++pp){
    int p = t + pp*256;
    int lrow = p >> 3, h = p & 7;
    int gn = blockIdx.x*64 + lrow;
    if (gn < N_NODES){
      const unsigned short* rp = &hls[lrow][h*16];
      uint2 A = *(const uint2*)rp;
      uint2 B = *(const uint2*)(rp+4);
      uint2 C = *(const uint2*)(rp+8);
      uint2 D = *(const uint2*)(rp+12);
      float c[16] = { blo(A.x), bhi(A.x), blo(A.y), bhi(A.y),
                      blo(B.x), bhi(B.x), blo(B.y), bhi(B.y),
                      blo(C.x), bhi(C.x), blo(C.y), bhi(C.y),
                      blo(D.x), bhi(D.x), blo(D.y), bhi(D.y) };
      const float* as = asrc + h*CPH;
      const float* ad = adst + h*CPH;
      float s0 = 0.f, s1 = 0.f;
      #pragma unroll
      for (int q = 0; q < 16; ++q){ s0 += c[q]*as[q]; s1 += c[q]*ad[q]; }
      ls[gn*8 + h] = s0;
      ld[gn*8 + h] = s1;
    }
  }
}

// ---------- attention + aggregation ----------
__global__ void k_agg(const int* __restrict__ off, const int* __restrict__ csrc,
                      const unsigned short* __restrict__ hb, const float* __restrict__ ls,
                      const float* __restrict__ ld, const float* __restrict__ bias,
                      unsigned short* __restrict__ outb){
  int wid = threadIdx.x >> 6, lane = threadIdx.x & 63;
  int n = blockIdx.x*4 + wid;
  if (n >= N_NODES) return;
  int rs = __builtin_amdgcn_readfirstlane(off[n]);
  int re = __builtin_amdgcn_readfirstlane(off[n+1]);
  int q = lane >> 4;               // quarter: which of 4 parallel edges
  int l = lane & 15;               // lane-in-quarter: channels l*8 .. l*8+7
  int h = l >> 1;                  // head of those channels
  float ldh = ld[n*8 + h];
  const uint4* hb4 = (const uint4*)hb;    // 16 uint4 per 256B row
  float ac0=0.f, ac1=0.f, ac2=0.f, ac3=0.f, ac4=0.f, ac5=0.f, ac6=0.f, ac7=0.f, dsum=0.f;
  #define AGG_BODY(J) { \
    int s = __shfl(sv, (J), 64); \
    float g = ls[s*8 + h]; \
    float ex = __expf(leaky(g + ldh)); \
    uint4 v = hb4[(size_t)s*16 + l]; \
    ac0 += ex*blo(v.x); ac1 += ex*bhi(v.x); \
    ac2 += ex*blo(v.y); ac3 += ex*bhi(v.y); \
    ac4 += ex*blo(v.z); ac5 += ex*bhi(v.z); \
    ac6 += ex*blo(v.w); ac7 += ex*bhi(v.w); \
    dsum += ex; }
  int nb = re - rs;
  for (int cb = 0; cb < nb; cb += 64){
    int cnt = nb - cb; if (cnt > 64) cnt = 64;
    int sv = csrc[rs + cb + (lane < cnt ? lane : 0)];   // one coalesced load / 64 edges
    int jj = 0;
    for (; jj + 16 <= cnt; jj += 16){
      AGG_BODY(jj+q) AGG_BODY(jj+q+4) AGG_BODY(jj+q+8) AGG_BODY(jj+q+12)
    }
    for (int j = jj + q; j < cnt; j += 4) AGG_BODY(j)
  }
  #undef AGG_BODY
  ac0 += __shfl_xor(ac0,16,64); ac0 += __shfl_xor(ac0,32,64);
  ac1 += __shfl_xor(ac1,16,64); ac1 += __shfl_xor(ac1,32,64);
  ac2 += __shfl_xor(ac2,16,64); ac2 += __shfl_xor(ac2,32,64);
  ac3 += __shfl_xor(ac3,16,64); ac3 += __shfl_xor(ac3,32,64);
  ac4 += __shfl_xor(ac4,16,64); ac4 += __shfl_xor(ac4,32,64);
  ac5 += __shfl_xor(ac5,16,64); ac5 += __shfl_xor(ac5,32,64);
  ac6 += __shfl_xor(ac6,16,64); ac6 += __shfl_xor(ac6,32,64);
  ac7 += __shfl_xor(ac7,16,64); ac7 += __shfl_xor(ac7,32,64);
  dsum += __shfl_xor(dsum,16,64); dsum += __shfl_xor(dsum,32,64);
  if (q == 0){
    float inv = 1.f/fmaxf(dsum, 1e-16f);
    float4 b0 = ((const float4*)bias)[l*2];
    float4 b1 = ((const float4*)bias)[l*2+1];
    uint4 o;
    o.x = (unsigned)f2bf(fmaxf(ac0*inv + b0.x, 0.f)) | ((unsigned)f2bf(fmaxf(ac1*inv + b0.y, 0.f)) << 16);
    o.y = (unsigned)f2bf(fmaxf(ac2*inv + b0.z, 0.f)) | ((unsigned)f2bf(fmaxf(ac3*inv + b0.w, 0.f)) << 16);
    o.z = (unsigned)f2bf(fmaxf(ac4*inv + b1.x, 0.f)) | ((unsigned)f2bf(fmaxf(ac5*inv + b1.y, 0.f)) << 16);
    o.w = (unsigned)f2bf(fmaxf(ac6*inv + b1.z, 0.f)) | ((unsigned)f2bf(fmaxf(ac7*inv + b1.w, 0.f)) << 16);
    ((uint4*)outb)[(size_t)n*16 + l] = o;
  }
}

// ---------- pooling + classify fused (bf16 input) ----------
__global__ void k_poolcls(const unsigned short* __restrict__ h, const int* __restrict__ goff,
                          const float* __restrict__ lw, const float* __restrict__ lb,
                          float* __restrict__ out){
  __shared__ float sh[4][HC];
  int g = blockIdx.x;
  int t = threadIdx.x, lane = t & 63, wv = t >> 6;
  int s = goff[g], epos = goff[g+1];
  float a0 = 0.f, a1 = 0.f;
  const ushort2* h2 = (const ushort2*)h;
  for (int n = s + wv; n < epos; n += 4){
    ushort2 v = h2[(size_t)n*64 + lane];
    a0 += bf2f(v.x); a1 += bf2f(v.y);
  }
  sh[wv][lane*2] = a0; sh[wv][lane*2+1] = a1;
  __syncthreads();
  if (wv == 0){
    int c0 = lane*2;
    float p0 = sh[0][c0] + sh[1][c0] + sh[2][c0] + sh[3][c0];
    float p1 = sh[0][c0+1] + sh[1][c0+1] + sh[2][c0+1] + sh[3][c0+1];
    int cntg = epos - s;
    float invc = 1.f/fmaxf((float)cntg, 1.f);
    float v0 = p0*invc, v1 = p1*invc;
    float l0 = v0*lw[c0*2+0] + v1*lw[(c0+1)*2+0];
    float l1 = v0*lw[c0*2+1] + v1*lw[(c0+1)*2+1];
    #pragma unroll
    for (int o = 32; o >= 1; o >>= 1){ l0 += __shfl_xor(l0,o,64); l1 += __shfl_xor(l1,o,64); }
    if (lane == 0){
      l0 += lb[0]; l1 += lb[1];
      float m = fmaxf(l0,l1);
      float e0 = __expf(l0-m), e1 = __expf(l1-m);
      float si = e0 + e1;
      out[g*2]   = e0/si;
      out[g*2+1] = e1/si;
    }
  }
}

extern "C" void kernel_launch(void* const* d_in, const int* in_sizes, int n_in,
                              void* d_out, int out_size, void* d_ws, size_t ws_size,
                              hipStream_t stream){
  const float* x   = (const float*)d_in[0];
  const int*   ei  = (const int*)d_in[1];
  const int*   bat = (const int*)d_in[2];
  const float* W1  = (const float*)d_in[3];
  const float* a1s = (const float*)d_in[4];
  const float* a1d = (const float*)d_in[5];
  const float* b1  = (const float*)d_in[6];
  const float* W2  = (const float*)d_in[7];
  const float* a2s = (const float*)d_in[8];
  const float* a2d = (const float*)d_in[9];
  const float* b2  = (const float*)d_in[10];
  const float* lw  = (const float*)d_in[11];
  const float* lb  = (const float*)d_in[12];
  float* out = (float*)d_out;

  char* w = (char*)d_ws;
  auto alloc = [&](size_t bytes)->void*{ void* p = (void*)w; w += (bytes + 511) & ~size_t(511); return p; };
  int* off    = (int*)alloc((size_t)(N_NODES+1)*4);
  int* cur    = (int*)alloc((size_t)N_NODES*4);
  int* cnt    = (int*)alloc((size_t)N_NODES*4);
  int* csrc   = (int*)alloc((size_t)E_TOTAL*4);
  int* goff   = (int*)alloc((size_t)(N_GRAPHS+1)*4);
  int* gpos   = (int*)alloc((size_t)NBUK*4);
  int* bsum   = (int*)alloc((size_t)(NB_SCAN+1)*4);
  unsigned* gbin = (unsigned*)alloc((size_t)NBUK*BCAP*4);
  unsigned short* w2t  = (unsigned short*)alloc((size_t)HC*HC*2);
  unsigned short* w1t  = (unsigned short*)alloc((size_t)HC*32*2);
  unsigned short* xbf  = (unsigned short*)alloc((size_t)N_NODES*32*2);
  unsigned short* hbf  = (unsigned short*)alloc((size_t)N_NODES*HC*2);
  unsigned short* hbf2 = (unsigned short*)alloc((size_t)N_NODES*HC*2);
  float* lsb  = (float*)alloc((size_t)N_NODES*HEADS*4);
  float* ldb  = (float*)alloc((size_t)N_NODES*HEADS*4);

  hipMemsetAsync(gpos, 0, (size_t)NBUK*4, stream);
  hipMemsetAsync(cnt, 0, (size_t)N_NODES*4, stream);

  // K1: bin(+node counts) | goff | w2t | x->bf16 | w1t
  k_pre  <<<NBIN_BLK + GOFF_BLK + WCONV_BLK + XCONV_BLK + W1CONV_BLK,BIN_TPB,0,stream>>>(
           ei, gpos, gbin, cnt, bat, goff, W2, w2t, x, xbf, W1, w1t);
  // scan cnt -> off, cur
  k_scan1<<<NB_SCAN,SCAN_B,0,stream>>>(cnt, off, bsum);
  k_scan2<<<1,256,0,stream>>>(bsum, NB_SCAN);
  k_scan3<<<(N_NODES+255)/256,256,0,stream>>>(off, bsum, cur);
  // layer-1 GEMM via MFMA (+fused logits)
  k_gemm_mfma<1><<<(N_NODES+63)/64,256,0,stream>>>(xbf, w1t, a1s, a1d, hbf, lsb, ldb);
  // CSR scatter (full-device parallel)
  k_csrs <<<NBUK*CSR_SPLIT,256,0,stream>>>(gpos, gbin, cur, csrc);

  // layer 1 aggregation
  k_agg  <<<(N_NODES+3)/4,256,0,stream>>>(off, csrc, hbf, lsb, ldb, b1, hbf2);
  // layer 2 (MFMA GEMM + fused logits)
  k_gemm_mfma<4><<<(N_NODES+63)/64,256,0,stream>>>(hbf2, w2t, a2s, a2d, hbf, lsb, ldb);
  k_agg  <<<(N_NODES+3)/4,256,0,stream>>>(off, csrc, hbf, lsb, ldb, b2, hbf2);

  // pooling + classifier
  k_poolcls<<<N_GRAPHS,256,0,stream>>>(hbf2, goff, lw, lb, out);
}

// Round 15
// 361.496 us; speedup vs baseline: 1.0265x; 1.0265x over previous
//
#include <hip/hip_runtime.h>
#include <math.h>

#define N_NODES 100000
#define N_EDGESI 1600000
#define E_TOTAL (N_EDGESI + N_NODES)
#define N_GRAPHS 2000
#define F_IN 16
#define HEADS 8
#define CPH 16
#define HC 128
#define NEG 0.2f
#define SCAN_B 1024
#define NB_SCAN ((N_NODES + SCAN_B - 1)/SCAN_B)   // 98

// bucketed scatter params
#define BSHIFT 9
#define BNODES (1<<BSHIFT)                         // 512 nodes per bucket
#define NBUK ((N_NODES + BNODES - 1)/BNODES)       // 196
#define NBUK_PAD 200                               // multiple of 8 -> XCD-stable mapping
#define BCAP 12288
#define BIN_EPT 8
#define BIN_TPB 256
#define BIN_EPB (BIN_EPT*BIN_TPB)                  // 2048
#define NBIN_BLK ((E_TOTAL + BIN_EPB - 1)/BIN_EPB) // 831
#define CSR_SPLIT 4

#define CNT_BLK ((E_TOTAL+255)/256)                // 6645
#define GOFF_BLK ((N_NODES+255)/256)               // 391
#define WCONV_BLK ((HC*HC)/256)                    // 64
#define XCONV_BLK ((N_NODES*4 + 255)/256)          // 1563
#define W1CONV_BLK ((HC*32)/256)                   // 16

typedef __bf16 bf16x8 __attribute__((ext_vector_type(8)));
typedef float  f32x4  __attribute__((ext_vector_type(4)));

__device__ __forceinline__ float leaky(float x){ return fmaxf(x, NEG*x); }
__device__ __forceinline__ float bf2f(unsigned short u){ return __uint_as_float(((unsigned)u)<<16); }
__device__ __forceinline__ unsigned short f2bf(float f){
  unsigned u = __float_as_uint(f);
  unsigned r = (u + 0x7fffu + ((u>>16)&1u)) >> 16;
  return (unsigned short)r;
}
__device__ __forceinline__ float blo(unsigned u){ return __uint_as_float(u<<16); }
__device__ __forceinline__ float bhi(unsigned u){ return __uint_as_float(u & 0xffff0000u); }

// ---------- K1: bin (2-pass, EPT=8) | node-count | goff | W2t | x->bf16 | W1t ----------
__global__ void k_pre(const int* __restrict__ ei, int* __restrict__ gpos, unsigned* __restrict__ gbin,
                      int* __restrict__ cnt_g,
                      const int* __restrict__ batch, int* __restrict__ goff,
                      const float* __restrict__ W2, unsigned short* __restrict__ w2t,
                      const float* __restrict__ x, unsigned short* __restrict__ xbf,
                      const float* __restrict__ W1, unsigned short* __restrict__ w1t){
  int blk = blockIdx.x;
  if (blk < NBIN_BLK){
    __shared__ int cnt[NBUK];     // pass-A bucket counts
    __shared__ int rnk[NBUK];     // pass-B rank cursors
    __shared__ int bbase[NBUK];   // global base per bucket for this block
    int t = threadIdx.x;
    for (int i = t; i < NBUK; i += BIN_TPB){ cnt[i] = 0; rnk[i] = 0; }
    __syncthreads();
    int base = blk*BIN_EPB;
    #pragma unroll
    for (int i = 0; i < BIN_EPT; ++i){
      int e = base + i*BIN_TPB + t;
      if (e < E_TOTAL){
        unsigned d = (e < N_EDGESI) ? (unsigned)ei[N_EDGESI + e] : (unsigned)(e - N_EDGESI);
        atomicAdd(&cnt[d >> BSHIFT], 1);
      }
    }
    __syncthreads();
    for (int i = t; i < NBUK; i += BIN_TPB){
      int v = cnt[i];
      bbase[i] = v ? atomicAdd(&gpos[i], v) : 0;
    }
    __syncthreads();
    #pragma unroll
    for (int i = 0; i < BIN_EPT; ++i){
      int e = base + i*BIN_TPB + t;
      if (e < E_TOTAL){
        unsigned s, d;
        if (e < N_EDGESI){ s = (unsigned)ei[e]; d = (unsigned)ei[N_EDGESI + e]; }
        else { s = d = (unsigned)(e - N_EDGESI); }
        int b = (int)(d >> BSHIFT);
        int r = atomicAdd(&rnk[b], 1);
        gbin[(size_t)b*BCAP + bbase[b] + r] = ((d & (BNODES-1u)) << 17) | s;
      }
    }
  } else if (blk < NBIN_BLK + CNT_BLK){
    int e = (blk - NBIN_BLK)*256 + threadIdx.x;
    if (e >= E_TOTAL) return;
    int d = (e < N_EDGESI) ? ei[N_EDGESI + e] : (e - N_EDGESI);
    atomicAdd(&cnt_g[d], 1);
  } else if (blk < NBIN_BLK + CNT_BLK + GOFF_BLK){
    int n = (blk - NBIN_BLK - CNT_BLK)*256 + threadIdx.x;
    if (n >= N_NODES) return;
    int b = batch[n];
    if (n == 0){ for (int g = 0; g <= b; ++g) goff[g] = 0; }
    int b1 = (n+1 < N_NODES) ? batch[n+1] : N_GRAPHS;
    for (int g = b+1; g <= b1; ++g) goff[g] = n+1;
  } else if (blk < NBIN_BLK + CNT_BLK + GOFF_BLK + WCONV_BLK){
    int i = (blk - NBIN_BLK - CNT_BLK - GOFF_BLK)*256 + threadIdx.x;  // c*128 + k
    if (i >= HC*HC) return;
    int c = i >> 7, k = i & 127;
    w2t[i] = f2bf(W2[k*HC + c]);
  } else if (blk < NBIN_BLK + CNT_BLK + GOFF_BLK + WCONV_BLK + XCONV_BLK){
    int p = (blk - NBIN_BLK - CNT_BLK - GOFF_BLK - WCONV_BLK)*256 + threadIdx.x;  // n*4+quad
    if (p >= N_NODES*4) return;
    int n = p >> 2, q = p & 3;
    float4 xv = ((const float4*)(x + n*F_IN))[q];
    ushort4 o; o.x = f2bf(xv.x); o.y = f2bf(xv.y); o.z = f2bf(xv.z); o.w = f2bf(xv.w);
    ((ushort4*)(xbf + (size_t)n*32))[q] = o;
    ushort4 z; z.x = 0; z.y = 0; z.z = 0; z.w = 0;
    ((ushort4*)(xbf + (size_t)n*32 + 16))[q] = z;
  } else {
    int i = (blk - NBIN_BLK - CNT_BLK - GOFF_BLK - WCONV_BLK - XCONV_BLK)*256 + threadIdx.x;
    if (i >= HC*32) return;
    int c = i >> 5, k = i & 31;
    w1t[i] = (k < F_IN) ? f2bf(W1[k*HC + c]) : (unsigned short)0;
  }
}

// ---------- scans ----------
__global__ void k_scan1(const int* __restrict__ cnt, int* __restrict__ off, int* __restrict__ bsum){
  __shared__ int ws[16];
  int b = blockIdx.x, t = threadIdx.x, lane = t & 63, wv = t >> 6;
  int i = b*SCAN_B + t;
  int v = (i < N_NODES) ? cnt[i] : 0;
  int sc = v;
  #pragma unroll
  for (int o=1;o<64;o<<=1){ int u = __shfl_up(sc, o, 64); if (lane >= o) sc += u; }
  if (lane==63) ws[wv] = sc;
  __syncthreads();
  if (wv==0 && lane<16){
    int w = ws[lane];
    #pragma unroll
    for (int o=1;o<16;o<<=1){ int u = __shfl_up(w,o,64); if (lane>=o) w += u; }
    ws[lane] = w;
  }
  __syncthreads();
  int base = wv ? ws[wv-1] : 0;
  if (i < N_NODES) off[i] = base + sc - v;
  if (t == SCAN_B-1) bsum[b] = ws[15];
}

__global__ void k_scan2(int* __restrict__ bsum, int nb){
  __shared__ int ws[4];
  int t = threadIdx.x, lane = t & 63, wv = t >> 6;
  int v = (t < nb) ? bsum[t] : 0;
  int sc = v;
  #pragma unroll
  for (int o=1;o<64;o<<=1){ int u = __shfl_up(sc,o,64); if (lane>=o) sc += u; }
  if (lane==63) ws[wv] = sc;
  __syncthreads();
  if (wv==0 && lane<4){
    int w = ws[lane];
    #pragma unroll
    for (int o=1;o<4;o<<=1){ int u = __shfl_up(w,o,64); if (lane>=o) w += u; }
    ws[lane] = w;
  }
  __syncthreads();
  int base = wv ? ws[wv-1] : 0;
  int excl = base + sc - v;
  int total = ws[3];
  __syncthreads();
  if (t < nb) bsum[t] = excl;
  if (t == nb) bsum[nb] = total;
}

__global__ void k_scan3(int* __restrict__ off, const int* __restrict__ bsum, int* __restrict__ cur){
  int i = blockIdx.x*256 + threadIdx.x;
  if (i < N_NODES){
    int v = off[i] + bsum[i>>10];
    off[i] = v; cur[i] = v;
  }
  if (i == 0) off[N_NODES] = bsum[NB_SCAN];
}

// ---------- scatter-only CSR finalize: XCD-local 4-way bucket split ----------
// bucket = blk % NBUK_PAD (200 ≡ 0 mod 8 -> all parts of a bucket on same XCD)
__global__ void k_csrs(const int* __restrict__ gpos, const unsigned* __restrict__ gbin,
                       int* __restrict__ cur, int* __restrict__ csrc){
  int b = blockIdx.x % NBUK_PAD, part = blockIdx.x / NBUK_PAD;
  if (b >= NBUK) return;
  int nb = gpos[b];
  int lo = (int)(((long long)nb*part)/CSR_SPLIT);
  int hi = (int)(((long long)nb*(part+1))/CSR_SPLIT);
  const unsigned* bb = gbin + (size_t)b*BCAP;
  int d0 = b << BSHIFT;
  for (int i = lo + threadIdx.x; i < hi; i += 256){
    unsigned en = bb[i];
    int p = atomicAdd(&cur[d0 + (int)(en >> 17)], 1);
    csrc[p] = (int)(en & 0x1ffffu);
  }
}

// ---------- GEMM via MFMA bf16 (both layers), fused logits via LDS stage ----------
template<int KS>
__global__ __launch_bounds__(256) void k_gemm_mfma(
                             const unsigned short* __restrict__ hin,
                             const unsigned short* __restrict__ wt,
                             const float* __restrict__ asrc, const float* __restrict__ adst,
                             unsigned short* __restrict__ hb,
                             float* __restrict__ ls, float* __restrict__ ld){
  __shared__ unsigned short hls[64][132];   // pad 132 -> conflict-free b64 reads
  const int KST = KS*32;
  int t = threadIdx.x, lane = t & 63, wv = t >> 6;
  int n0 = blockIdx.x*64 + wv*16;
  int rowl = lane & 15, kgrp = lane >> 4;
  int row = n0 + rowl;
  int rowc = (row < N_NODES) ? row : (N_NODES-1);
  bf16x8 a[KS];
  #pragma unroll
  for (int ks = 0; ks < KS; ++ks)
    a[ks] = *(const bf16x8*)(hin + (size_t)rowc*KST + ks*32 + kgrp*8);
  #pragma unroll
  for (int ct = 0; ct < 8; ++ct){
    f32x4 acc = {0.f, 0.f, 0.f, 0.f};
    int col = ct*16 + rowl;
    #pragma unroll
    for (int ks = 0; ks < KS; ++ks){
      bf16x8 b = *(const bf16x8*)(wt + (size_t)col*KST + ks*32 + kgrp*8);
      acc = __builtin_amdgcn_mfma_f32_16x16x32_bf16(a[ks], b, acc, 0, 0, 0);
    }
    #pragma unroll
    for (int r = 0; r < 4; ++r){
      int lrow = wv*16 + kgrp*4 + r;
      int ro = n0 + kgrp*4 + r;
      unsigned short hv = f2bf(acc[r]);
      hls[lrow][col] = hv;
      if (ro < N_NODES) hb[(size_t)ro*HC + col] = hv;
    }
  }
  __syncthreads();
  #pragma unroll
  for (int pp = 0; pp < 2; ++pp){
    int p = t + pp*256;
    int lrow = p >> 3, h = p & 7;
    int gn = blockIdx.x*64 + lrow;
    if (gn < N_NODES){
      const unsigned short* rp = &hls[lrow][h*16];
      uint2 A = *(const uint2*)rp;
      uint2 B = *(const uint2*)(rp+4);
      uint2 C = *(const uint2*)(rp+8);
      uint2 D = *(const uint2*)(rp+12);
      float c[16] = { blo(A.x), bhi(A.x), blo(A.y), bhi(A.y),
                      blo(B.x), bhi(B.x), blo(B.y), bhi(B.y),
                      blo(C.x), bhi(C.x), blo(C.y), bhi(C.y),
                      blo(D.x), bhi(D.x), blo(D.y), bhi(D.y) };
      const float* as = asrc + h*CPH;
      const float* ad = adst + h*CPH;
      float s0 = 0.f, s1 = 0.f;
      #pragma unroll
      for (int q = 0; q < 16; ++q){ s0 += c[q]*as[q]; s1 += c[q]*ad[q]; }
      ls[gn*8 + h] = s0;
      ld[gn*8 + h] = s1;
    }
  }
}

// ---------- attention + aggregation ----------
__global__ void k_agg(const int* __restrict__ off, const int* __restrict__ csrc,
                      const unsigned short* __restrict__ hb, const float* __restrict__ ls,
                      const float* __restrict__ ld, const float* __restrict__ bias,
                      unsigned short* __restrict__ outb){
  int wid = threadIdx.x >> 6, lane = threadIdx.x & 63;
  int n = blockIdx.x*4 + wid;
  if (n >= N_NODES) return;
  int rs = __builtin_amdgcn_readfirstlane(off[n]);
  int re = __builtin_amdgcn_readfirstlane(off[n+1]);
  int q = lane >> 4;               // quarter: which of 4 parallel edges
  int l = lane & 15;               // lane-in-quarter: channels l*8 .. l*8+7
  int h = l >> 1;                  // head of those channels
  float ldh = ld[n*8 + h];
  const uint4* hb4 = (const uint4*)hb;    // 16 uint4 per 256B row
  float ac0=0.f, ac1=0.f, ac2=0.f, ac3=0.f, ac4=0.f, ac5=0.f, ac6=0.f, ac7=0.f, dsum=0.f;
  #define AGG_BODY(J) { \
    int s = __shfl(sv, (J), 64); \
    float g = ls[s*8 + h]; \
    float ex = __expf(leaky(g + ldh)); \
    uint4 v = hb4[(size_t)s*16 + l]; \
    ac0 += ex*blo(v.x); ac1 += ex*bhi(v.x); \
    ac2 += ex*blo(v.y); ac3 += ex*bhi(v.y); \
    ac4 += ex*blo(v.z); ac5 += ex*bhi(v.z); \
    ac6 += ex*blo(v.w); ac7 += ex*bhi(v.w); \
    dsum += ex; }
  int nb = re - rs;
  for (int cb = 0; cb < nb; cb += 64){
    int cnt = nb - cb; if (cnt > 64) cnt = 64;
    int sv = csrc[rs + cb + (lane < cnt ? lane : 0)];   // one coalesced load / 64 edges
    int jj = 0;
    for (; jj + 16 <= cnt; jj += 16){
      AGG_BODY(jj+q) AGG_BODY(jj+q+4) AGG_BODY(jj+q+8) AGG_BODY(jj+q+12)
    }
    for (int j = jj + q; j < cnt; j += 4) AGG_BODY(j)
  }
  #undef AGG_BODY
  ac0 += __shfl_xor(ac0,16,64); ac0 += __shfl_xor(ac0,32,64);
  ac1 += __shfl_xor(ac1,16,64); ac1 += __shfl_xor(ac1,32,64);
  ac2 += __shfl_xor(ac2,16,64); ac2 += __shfl_xor(ac2,32,64);
  ac3 += __shfl_xor(ac3,16,64); ac3 += __shfl_xor(ac3,32,64);
  ac4 += __shfl_xor(ac4,16,64); ac4 += __shfl_xor(ac4,32,64);
  ac5 += __shfl_xor(ac5,16,64); ac5 += __shfl_xor(ac5,32,64);
  ac6 += __shfl_xor(ac6,16,64); ac6 += __shfl_xor(ac6,32,64);
  ac7 += __shfl_xor(ac7,16,64); ac7 += __shfl_xor(ac7,32,64);
  dsum += __shfl_xor(dsum,16,64); dsum += __shfl_xor(dsum,32,64);
  if (q == 0){
    float inv = 1.f/fmaxf(dsum, 1e-16f);
    float4 b0 = ((const float4*)bias)[l*2];
    float4 b1 = ((const float4*)bias)[l*2+1];
    uint4 o;
    o.x = (unsigned)f2bf(fmaxf(ac0*inv + b0.x, 0.f)) | ((unsigned)f2bf(fmaxf(ac1*inv + b0.y, 0.f)) << 16);
    o.y = (unsigned)f2bf(fmaxf(ac2*inv + b0.z, 0.f)) | ((unsigned)f2bf(fmaxf(ac3*inv + b0.w, 0.f)) << 16);
    o.z = (unsigned)f2bf(fmaxf(ac4*inv + b1.x, 0.f)) | ((unsigned)f2bf(fmaxf(ac5*inv + b1.y, 0.f)) << 16);
    o.w = (unsigned)f2bf(fmaxf(ac6*inv + b1.z, 0.f)) | ((unsigned)f2bf(fmaxf(ac7*inv + b1.w, 0.f)) << 16);
    ((uint4*)outb)[(size_t)n*16 + l] = o;
  }
}

// ---------- pooling + classify fused (bf16 input) ----------
__global__ void k_poolcls(const unsigned short* __restrict__ h, const int* __restrict__ goff,
                          const float* __restrict__ lw, const float* __restrict__ lb,
                          float* __restrict__ out){
  __shared__ float sh[4][HC];
  int g = blockIdx.x;
  int t = threadIdx.x, lane = t & 63, wv = t >> 6;
  int s = goff[g], epos = goff[g+1];
  float a0 = 0.f, a1 = 0.f;
  const ushort2* h2 = (const ushort2*)h;
  for (int n = s + wv; n < epos; n += 4){
    ushort2 v = h2[(size_t)n*64 + lane];
    a0 += bf2f(v.x); a1 += bf2f(v.y);
  }
  sh[wv][lane*2] = a0; sh[wv][lane*2+1] = a1;
  __syncthreads();
  if (wv == 0){
    int c0 = lane*2;
    float p0 = sh[0][c0] + sh[1][c0] + sh[2][c0] + sh[3][c0];
    float p1 = sh[0][c0+1] + sh[1][c0+1] + sh[2][c0+1] + sh[3][c0+1];
    int cntg = epos - s;
    float invc = 1.f/fmaxf((float)cntg, 1.f);
    float v0 = p0*invc, v1 = p1*invc;
    float l0 = v0*lw[c0*2+0] + v1*lw[(c0+1)*2+0];
    float l1 = v0*lw[c0*2+1] + v1*lw[(c0+1)*2+1];
    #pragma unroll
    for (int o = 32; o >= 1; o >>= 1){ l0 += __shfl_xor(l0,o,64); l1 += __shfl_xor(l1,o,64); }
    if (lane == 0){
      l0 += lb[0]; l1 += lb[1];
      float m = fmaxf(l0,l1);
      float e0 = __expf(l0-m), e1 = __expf(l1-m);
      float si = e0 + e1;
      out[g*2]   = e0/si;
      out[g*2+1] = e1/si;
    }
  }
}

extern "C" void kernel_launch(void* const* d_in, const int* in_sizes, int n_in,
                              void* d_out, int out_size, void* d_ws, size_t ws_size,
                              hipStream_t stream){
  const float* x   = (const float*)d_in[0];
  const int*   ei  = (const int*)d_in[1];
  const int*   bat = (const int*)d_in[2];
  const float* W1  = (const float*)d_in[3];
  const float* a1s = (const float*)d_in[4];
  const float* a1d = (const float*)d_in[5];
  const float* b1  = (const float*)d_in[6];
  const float* W2  = (const float*)d_in[7];
  const float* a2s = (const float*)d_in[8];
  const float* a2d = (const float*)d_in[9];
  const float* b2  = (const float*)d_in[10];
  const float* lw  = (const float*)d_in[11];
  const float* lb  = (const float*)d_in[12];
  float* out = (float*)d_out;

  char* w = (char*)d_ws;
  auto alloc = [&](size_t bytes)->void*{ void* p = (void*)w; w += (bytes + 511) & ~size_t(511); return p; };
  int* off    = (int*)alloc((size_t)(N_NODES+1)*4);
  int* cur    = (int*)alloc((size_t)N_NODES*4);
  int* cnt    = (int*)alloc((size_t)N_NODES*4);
  int* csrc   = (int*)alloc((size_t)E_TOTAL*4);
  int* goff   = (int*)alloc((size_t)(N_GRAPHS+1)*4);
  int* gpos   = (int*)alloc((size_t)NBUK*4);
  int* bsum   = (int*)alloc((size_t)(NB_SCAN+1)*4);
  unsigned* gbin = (unsigned*)alloc((size_t)NBUK*BCAP*4);
  unsigned short* w2t  = (unsigned short*)alloc((size_t)HC*HC*2);
  unsigned short* w1t  = (unsigned short*)alloc((size_t)HC*32*2);
  unsigned short* xbf  = (unsigned short*)alloc((size_t)N_NODES*32*2);
  unsigned short* hbf  = (unsigned short*)alloc((size_t)N_NODES*HC*2);
  unsigned short* hbf2 = (unsigned short*)alloc((size_t)N_NODES*HC*2);
  float* lsb  = (float*)alloc((size_t)N_NODES*HEADS*4);
  float* ldb  = (float*)alloc((size_t)N_NODES*HEADS*4);

  hipMemsetAsync(gpos, 0, (size_t)NBUK*4, stream);
  hipMemsetAsync(cnt, 0, (size_t)N_NODES*4, stream);

  // K1: bin | node-count | goff | w2t | x->bf16 | w1t
  k_pre  <<<NBIN_BLK + CNT_BLK + GOFF_BLK + WCONV_BLK + XCONV_BLK + W1CONV_BLK,BIN_TPB,0,stream>>>(
           ei, gpos, gbin, cnt, bat, goff, W2, w2t, x, xbf, W1, w1t);
  // scan cnt -> off, cur
  k_scan1<<<NB_SCAN,SCAN_B,0,stream>>>(cnt, off, bsum);
  k_scan2<<<1,256,0,stream>>>(bsum, NB_SCAN);
  k_scan3<<<(N_NODES+255)/256,256,0,stream>>>(off, bsum, cur);
  // layer-1 GEMM via MFMA (+fused logits) — independent of scatter
  k_gemm_mfma<1><<<(N_NODES+63)/64,256,0,stream>>>(xbf, w1t, a1s, a1d, hbf, lsb, ldb);
  // CSR scatter (XCD-local split)
  k_csrs <<<NBUK_PAD*CSR_SPLIT,256,0,stream>>>(gpos, gbin, cur, csrc);

  // layer 1 aggregation
  k_agg  <<<(N_NODES+3)/4,256,0,stream>>>(off, csrc, hbf, lsb, ldb, b1, hbf2);
  // layer 2 (MFMA GEMM + fused logits)
  k_gemm_mfma<4><<<(N_NODES+63)/64,256,0,stream>>>(hbf2, w2t, a2s, a2d, hbf, lsb, ldb);
  k_agg  <<<(N_NODES+3)/4,256,0,stream>>>(off, csrc, hbf, lsb, ldb, b2, hbf2);

  // pooling + classifier
  k_poolcls<<<N_GRAPHS,256,0,stream>>>(hbf2, goff, lw, lb, out);
}

// Round 16
// 287.461 us; speedup vs baseline: 1.2909x; 1.2575x over previous
//
#include <hip/hip_runtime.h>
#include <math.h>

#define N_NODES 100000
#define N_EDGESI 1600000
#define E_TOTAL (N_EDGESI + N_NODES)
#define N_GRAPHS 2000
#define F_IN 16
#define HEADS 8
#define CPH 16
#define HC 128
#define NEG 0.2f
#define SCAN_B 1024

// bucketed scatter params
#define BSHIFT 9
#define BNODES (1<<BSHIFT)                         // 512 nodes per bucket
#define NBUK ((N_NODES + BNODES - 1)/BNODES)       // 196
#define BCAP 12288
#define BIN_EPT 8
#define BIN_TPB 256
#define BIN_EPB (BIN_EPT*BIN_TPB)                  // 2048
#define NBIN_BLK ((E_TOTAL + BIN_EPB - 1)/BIN_EPB) // 831
#define CSR_SPLIT 4
#define CNT4_LEN (NBUK*BNODES*CSR_SPLIT)           // 401408
#define NB_SCAN4 ((CNT4_LEN + SCAN_B - 1)/SCAN_B)  // 392

#define GOFF_BLK ((N_NODES+255)/256)               // 391
#define WCONV_BLK ((HC*HC)/256)                    // 64
#define XCONV_BLK ((N_NODES*4 + 255)/256)          // 1563
#define W1CONV_BLK ((HC*32)/256)                   // 16

typedef __bf16 bf16x8 __attribute__((ext_vector_type(8)));
typedef float  f32x4  __attribute__((ext_vector_type(4)));

__device__ __forceinline__ float leaky(float x){ return fmaxf(x, NEG*x); }
__device__ __forceinline__ float bf2f(unsigned short u){ return __uint_as_float(((unsigned)u)<<16); }
__device__ __forceinline__ unsigned short f2bf(float f){
  unsigned u = __float_as_uint(f);
  unsigned r = (u + 0x7fffu + ((u>>16)&1u)) >> 16;
  return (unsigned short)r;
}
__device__ __forceinline__ float blo(unsigned u){ return __uint_as_float(u<<16); }
__device__ __forceinline__ float bhi(unsigned u){ return __uint_as_float(u & 0xffff0000u); }

// ---------- K1 (round-12 version): bin (LDS counting sort) | goff | W2t | x->bf16 | W1t ----------
__global__ void k_pre(const int* __restrict__ ei, int* __restrict__ gpos, unsigned* __restrict__ gbin,
                      const int* __restrict__ batch, int* __restrict__ goff,
                      const float* __restrict__ W2, unsigned short* __restrict__ w2t,
                      const float* __restrict__ x, unsigned short* __restrict__ xbf,
                      const float* __restrict__ W1, unsigned short* __restrict__ w1t){
  int blk = blockIdx.x;
  if (blk < NBIN_BLK){
    __shared__ int cnt[NBUK];
    __shared__ int lofs[NBUK];
    __shared__ int bbase[NBUK];
    __shared__ int ws[4];
    __shared__ unsigned sorted[BIN_EPB];     // 8 KB
    __shared__ unsigned short sbkt[BIN_EPB]; // 4 KB
    int t = threadIdx.x;
    for (int i = t; i < NBUK; i += BIN_TPB) cnt[i] = 0;
    __syncthreads();
    int base = blk*BIN_EPB;
    unsigned entry[BIN_EPT]; int ebkt[BIN_EPT]; int erank[BIN_EPT];
    #pragma unroll
    for (int i = 0; i < BIN_EPT; ++i){
      int e = base + i*BIN_TPB + t;
      if (e < E_TOTAL){
        unsigned s, d;
        if (e < N_EDGESI){ s = (unsigned)ei[e]; d = (unsigned)ei[N_EDGESI + e]; }
        else { s = d = (unsigned)(e - N_EDGESI); }
        int b = (int)(d >> BSHIFT);
        erank[i] = atomicAdd(&cnt[b], 1);
        ebkt[i] = b;
        entry[i] = ((d & (BNODES-1u)) << 17) | s;
      } else ebkt[i] = -1;
    }
    __syncthreads();
    {
      int lane = t & 63, wv = t >> 6;
      int v = (t < NBUK) ? cnt[t] : 0;
      int sc = v;
      #pragma unroll
      for (int o = 1; o < 64; o <<= 1){ int u = __shfl_up(sc, o, 64); if (lane >= o) sc += u; }
      if (lane == 63) ws[wv] = sc;
      __syncthreads();
      if (wv == 0 && lane < 4){
        int w2v = ws[lane];
        #pragma unroll
        for (int o = 1; o < 4; o <<= 1){ int u = __shfl_up(w2v, o, 64); if (lane >= o) w2v += u; }
        ws[lane] = w2v;
      }
      __syncthreads();
      if (t < NBUK){
        lofs[t] = (wv ? ws[wv-1] : 0) + sc - v;
        bbase[t] = v ? atomicAdd(&gpos[t], v) : 0;
      }
    }
    __syncthreads();
    #pragma unroll
    for (int i = 0; i < BIN_EPT; ++i){
      if (ebkt[i] >= 0){
        int p = lofs[ebkt[i]] + erank[i];
        sorted[p] = entry[i];
        sbkt[p] = (unsigned short)ebkt[i];
      }
    }
    __syncthreads();
    int nval = E_TOTAL - base; if (nval > BIN_EPB) nval = BIN_EPB;
    for (int i = t; i < nval; i += BIN_TPB){
      int b = sbkt[i];
      gbin[(size_t)b*BCAP + bbase[b] + (i - lofs[b])] = sorted[i];
    }
  } else if (blk < NBIN_BLK + GOFF_BLK){
    int n = (blk - NBIN_BLK)*256 + threadIdx.x;
    if (n >= N_NODES) return;
    int b = batch[n];
    if (n == 0){ for (int g = 0; g <= b; ++g) goff[g] = 0; }
    int b1 = (n+1 < N_NODES) ? batch[n+1] : N_GRAPHS;
    for (int g = b+1; g <= b1; ++g) goff[g] = n+1;
  } else if (blk < NBIN_BLK + GOFF_BLK + WCONV_BLK){
    int i = (blk - NBIN_BLK - GOFF_BLK)*256 + threadIdx.x;  // c*128 + k
    if (i >= HC*HC) return;
    int c = i >> 7, k = i & 127;
    w2t[i] = f2bf(W2[k*HC + c]);
  } else if (blk < NBIN_BLK + GOFF_BLK + WCONV_BLK + XCONV_BLK){
    int p = (blk - NBIN_BLK - GOFF_BLK - WCONV_BLK)*256 + threadIdx.x;  // n*4 + quad
    if (p >= N_NODES*4) return;
    int n = p >> 2, q = p & 3;
    float4 xv = ((const float4*)(x + n*F_IN))[q];
    ushort4 o; o.x = f2bf(xv.x); o.y = f2bf(xv.y); o.z = f2bf(xv.z); o.w = f2bf(xv.w);
    ((ushort4*)(xbf + (size_t)n*32))[q] = o;
    ushort4 z; z.x = 0; z.y = 0; z.z = 0; z.w = 0;
    ((ushort4*)(xbf + (size_t)n*32 + 16))[q] = z;
  } else {
    int i = (blk - NBIN_BLK - GOFF_BLK - WCONV_BLK - XCONV_BLK)*256 + threadIdx.x;  // c*32+k
    if (i >= HC*32) return;
    int c = i >> 5, k = i & 31;
    w1t[i] = (k < F_IN) ? f2bf(W1[k*HC + c]) : (unsigned short)0;
  }
}

// ---------- per-(node,quarter) counts: block (b,p) owns its quarter, plain writes ----------
__global__ void k_cnt4(const int* __restrict__ gpos, const unsigned* __restrict__ gbin,
                       int* __restrict__ cnt4){
  __shared__ int lc[BNODES];
  int b = blockIdx.x >> 2, p = blockIdx.x & 3;
  int t = threadIdx.x;
  for (int i = t; i < BNODES; i += 256) lc[i] = 0;
  __syncthreads();
  int nb = gpos[b];
  int lo = (int)(((long long)nb*p)/CSR_SPLIT);
  int hi = (int)(((long long)nb*(p+1))/CSR_SPLIT);
  const unsigned* bb = gbin + (size_t)b*BCAP;
  for (int i = lo + t; i < hi; i += 256) atomicAdd(&lc[bb[i] >> 17], 1);
  __syncthreads();
  int base = (b << BSHIFT)*CSR_SPLIT + p;
  for (int i = t; i < BNODES; i += 256) cnt4[base + i*CSR_SPLIT] = lc[i];
}

// ---------- scans over cnt4 (401408) ----------
__global__ void k_scan1(const int* __restrict__ cnt, int* __restrict__ ps, int* __restrict__ bsum){
  __shared__ int ws[16];
  int b = blockIdx.x, t = threadIdx.x, lane = t & 63, wv = t >> 6;
  int i = b*SCAN_B + t;
  int v = (i < CNT4_LEN) ? cnt[i] : 0;
  int sc = v;
  #pragma unroll
  for (int o=1;o<64;o<<=1){ int u = __shfl_up(sc, o, 64); if (lane >= o) sc += u; }
  if (lane==63) ws[wv] = sc;
  __syncthreads();
  if (wv==0 && lane<16){
    int w = ws[lane];
    #pragma unroll
    for (int o=1;o<16;o<<=1){ int u = __shfl_up(w,o,64); if (lane>=o) w += u; }
    ws[lane] = w;
  }
  __syncthreads();
  int base = wv ? ws[wv-1] : 0;
  if (i < CNT4_LEN) ps[i] = base + sc - v;
  if (t == SCAN_B-1) bsum[b] = ws[15];
}

__global__ void k_scan2(int* __restrict__ bsum, int nb){   // nb <= 512, 512 threads
  __shared__ int ws[8];
  int t = threadIdx.x, lane = t & 63, wv = t >> 6;
  int v = (t < nb) ? bsum[t] : 0;
  int sc = v;
  #pragma unroll
  for (int o=1;o<64;o<<=1){ int u = __shfl_up(sc,o,64); if (lane>=o) sc += u; }
  if (lane==63) ws[wv] = sc;
  __syncthreads();
  if (wv==0 && lane<8){
    int w = ws[lane];
    #pragma unroll
    for (int o=1;o<8;o<<=1){ int u = __shfl_up(w,o,64); if (lane>=o) w += u; }
    ws[lane] = w;
  }
  __syncthreads();
  int base = wv ? ws[wv-1] : 0;
  if (t < nb) bsum[t] = base + sc - v;
}

__global__ void k_scan3(int* __restrict__ ps, const int* __restrict__ bsum, int* __restrict__ offc){
  int i = blockIdx.x*256 + threadIdx.x;
  if (i < CNT4_LEN){
    int v = ps[i] + bsum[i>>10];
    ps[i] = v;
    if ((i & 3) == 0){
      int n = i >> 2;
      if (n < N_NODES) offc[n] = v;
    }
  }
  if (i == 0) offc[N_NODES] = E_TOTAL;
}

// ---------- scatter: block (b,p) private LDS cursors from ps, LDS-only atomics ----------
__global__ void k_scat4(const int* __restrict__ gpos, const unsigned* __restrict__ gbin,
                        const int* __restrict__ ps, int* __restrict__ csrc){
  __shared__ int lcur[BNODES];
  int b = blockIdx.x >> 2, p = blockIdx.x & 3;
  int t = threadIdx.x;
  int base = (b << BSHIFT)*CSR_SPLIT + p;
  for (int i = t; i < BNODES; i += 256) lcur[i] = ps[base + i*CSR_SPLIT];
  __syncthreads();
  int nb = gpos[b];
  int lo = (int)(((long long)nb*p)/CSR_SPLIT);
  int hi = (int)(((long long)nb*(p+1))/CSR_SPLIT);
  const unsigned* bb = gbin + (size_t)b*BCAP;
  for (int i = lo + t; i < hi; i += 256){
    unsigned en = bb[i];
    int pos = atomicAdd(&lcur[en >> 17], 1);
    csrc[pos] = (int)(en & 0x1ffffu);
  }
}

// ---------- GEMM via MFMA bf16 (both layers), fused logits via LDS stage ----------
template<int KS>
__global__ __launch_bounds__(256) void k_gemm_mfma(
                             const unsigned short* __restrict__ hin,
                             const unsigned short* __restrict__ wt,
                             const float* __restrict__ asrc, const float* __restrict__ adst,
                             unsigned short* __restrict__ hb,
                             float* __restrict__ ls, float* __restrict__ ld){
  __shared__ unsigned short hls[64][132];   // pad 132 -> conflict-free b64 reads
  const int KST = KS*32;
  int t = threadIdx.x, lane = t & 63, wv = t >> 6;
  int n0 = blockIdx.x*64 + wv*16;
  int rowl = lane & 15, kgrp = lane >> 4;
  int row = n0 + rowl;
  int rowc = (row < N_NODES) ? row : (N_NODES-1);
  bf16x8 a[KS];
  #pragma unroll
  for (int ks = 0; ks < KS; ++ks)
    a[ks] = *(const bf16x8*)(hin + (size_t)rowc*KST + ks*32 + kgrp*8);
  #pragma unroll
  for (int ct = 0; ct < 8; ++ct){
    f32x4 acc = {0.f, 0.f, 0.f, 0.f};
    int col = ct*16 + rowl;
    #pragma unroll
    for (int ks = 0; ks < KS; ++ks){
      bf16x8 b = *(const bf16x8*)(wt + (size_t)col*KST + ks*32 + kgrp*8);
      acc = __builtin_amdgcn_mfma_f32_16x16x32_bf16(a[ks], b, acc, 0, 0, 0);
    }
    #pragma unroll
    for (int r = 0; r < 4; ++r){
      int lrow = wv*16 + kgrp*4 + r;
      int ro = n0 + kgrp*4 + r;
      unsigned short hv = f2bf(acc[r]);
      hls[lrow][col] = hv;
      if (ro < N_NODES) hb[(size_t)ro*HC + col] = hv;
    }
  }
  __syncthreads();
  #pragma unroll
  for (int pp = 0; pp < 2; ++pp){
    int p = t + pp*256;
    int lrow = p >> 3, h = p & 7;
    int gn = blockIdx.x*64 + lrow;
    if (gn < N_NODES){
      const unsigned short* rp = &hls[lrow][h*16];
      uint2 A = *(const uint2*)rp;
      uint2 B = *(const uint2*)(rp+4);
      uint2 C = *(const uint2*)(rp+8);
      uint2 D = *(const uint2*)(rp+12);
      float c[16] = { blo(A.x), bhi(A.x), blo(A.y), bhi(A.y),
                      blo(B.x), bhi(B.x), blo(B.y), bhi(B.y),
                      blo(C.x), bhi(C.x), blo(C.y), bhi(C.y),
                      blo(D.x), bhi(D.x), blo(D.y), bhi(D.y) };
      const float* as = asrc + h*CPH;
      const float* ad = adst + h*CPH;
      float s0 = 0.f, s1 = 0.f;
      #pragma unroll
      for (int q = 0; q < 16; ++q){ s0 += c[q]*as[q]; s1 += c[q]*ad[q]; }
      ls[gn*8 + h] = s0;
      ld[gn*8 + h] = s1;
    }
  }
}

// ---------- attention + aggregation ----------
__global__ void k_agg(const int* __restrict__ off, const int* __restrict__ csrc,
                      const unsigned short* __restrict__ hb, const float* __restrict__ ls,
                      const float* __restrict__ ld, const float* __restrict__ bias,
                      unsigned short* __restrict__ outb){
  int wid = threadIdx.x >> 6, lane = threadIdx.x & 63;
  int n = blockIdx.x*4 + wid;
  if (n >= N_NODES) return;
  int rs = __builtin_amdgcn_readfirstlane(off[n]);
  int re = __builtin_amdgcn_readfirstlane(off[n+1]);
  int q = lane >> 4;               // quarter: which of 4 parallel edges
  int l = lane & 15;               // lane-in-quarter: channels l*8 .. l*8+7
  int h = l >> 1;                  // head of those channels
  float ldh = ld[n*8 + h];
  const uint4* hb4 = (const uint4*)hb;    // 16 uint4 per 256B row
  float ac0=0.f, ac1=0.f, ac2=0.f, ac3=0.f, ac4=0.f, ac5=0.f, ac6=0.f, ac7=0.f, dsum=0.f;
  #define AGG_BODY(J) { \
    int s = __shfl(sv, (J), 64); \
    float g = ls[s*8 + h]; \
    float ex = __expf(leaky(g + ldh)); \
    uint4 v = hb4[(size_t)s*16 + l]; \
    ac0 += ex*blo(v.x); ac1 += ex*bhi(v.x); \
    ac2 += ex*blo(v.y); ac3 += ex*bhi(v.y); \
    ac4 += ex*blo(v.z); ac5 += ex*bhi(v.z); \
    ac6 += ex*blo(v.w); ac7 += ex*bhi(v.w); \
    dsum += ex; }
  int nb = re - rs;
  for (int cb = 0; cb < nb; cb += 64){
    int cnt = nb - cb; if (cnt > 64) cnt = 64;
    int sv = csrc[rs + cb + (lane < cnt ? lane : 0)];   // one coalesced load / 64 edges
    int jj = 0;
    for (; jj + 16 <= cnt; jj += 16){
      AGG_BODY(jj+q) AGG_BODY(jj+q+4) AGG_BODY(jj+q+8) AGG_BODY(jj+q+12)
    }
    for (int j = jj + q; j < cnt; j += 4) AGG_BODY(j)
  }
  #undef AGG_BODY
  ac0 += __shfl_xor(ac0,16,64); ac0 += __shfl_xor(ac0,32,64);
  ac1 += __shfl_xor(ac1,16,64); ac1 += __shfl_xor(ac1,32,64);
  ac2 += __shfl_xor(ac2,16,64); ac2 += __shfl_xor(ac2,32,64);
  ac3 += __shfl_xor(ac3,16,64); ac3 += __shfl_xor(ac3,32,64);
  ac4 += __shfl_xor(ac4,16,64); ac4 += __shfl_xor(ac4,32,64);
  ac5 += __shfl_xor(ac5,16,64); ac5 += __shfl_xor(ac5,32,64);
  ac6 += __shfl_xor(ac6,16,64); ac6 += __shfl_xor(ac6,32,64);
  ac7 += __shfl_xor(ac7,16,64); ac7 += __shfl_xor(ac7,32,64);
  dsum += __shfl_xor(dsum,16,64); dsum += __shfl_xor(dsum,32,64);
  if (q == 0){
    float inv = 1.f/fmaxf(dsum, 1e-16f);
    float4 b0 = ((const float4*)bias)[l*2];
    float4 b1 = ((const float4*)bias)[l*2+1];
    uint4 o;
    o.x = (unsigned)f2bf(fmaxf(ac0*inv + b0.x, 0.f)) | ((unsigned)f2bf(fmaxf(ac1*inv + b0.y, 0.f)) << 16);
    o.y = (unsigned)f2bf(fmaxf(ac2*inv + b0.z, 0.f)) | ((unsigned)f2bf(fmaxf(ac3*inv + b0.w, 0.f)) << 16);
    o.z = (unsigned)f2bf(fmaxf(ac4*inv + b1.x, 0.f)) | ((unsigned)f2bf(fmaxf(ac5*inv + b1.y, 0.f)) << 16);
    o.w = (unsigned)f2bf(fmaxf(ac6*inv + b1.z, 0.f)) | ((unsigned)f2bf(fmaxf(ac7*inv + b1.w, 0.f)) << 16);
    ((uint4*)outb)[(size_t)n*16 + l] = o;
  }
}

// ---------- pooling + classify fused (bf16 input) ----------
__global__ void k_poolcls(const unsigned short* __restrict__ h, const int* __restrict__ goff,
                          const float* __restrict__ lw, const float* __restrict__ lb,
                          float* __restrict__ out){
  __shared__ float sh[4][HC];
  int g = blockIdx.x;
  int t = threadIdx.x, lane = t & 63, wv = t >> 6;
  int s = goff[g], epos = goff[g+1];
  float a0 = 0.f, a1 = 0.f;
  const ushort2* h2 = (const ushort2*)h;
  for (int n = s + wv; n < epos; n += 4){
    ushort2 v = h2[(size_t)n*64 + lane];
    a0 += bf2f(v.x); a1 += bf2f(v.y);
  }
  sh[wv][lane*2] = a0; sh[wv][lane*2+1] = a1;
  __syncthreads();
  if (wv == 0){
    int c0 = lane*2;
    float p0 = sh[0][c0] + sh[1][c0] + sh[2][c0] + sh[3][c0];
    float p1 = sh[0][c0+1] + sh[1][c0+1] + sh[2][c0+1] + sh[3][c0+1];
    int cntg = epos - s;
    float invc = 1.f/fmaxf((float)cntg, 1.f);
    float v0 = p0*invc, v1 = p1*invc;
    float l0 = v0*lw[c0*2+0] + v1*lw[(c0+1)*2+0];
    float l1 = v0*lw[c0*2+1] + v1*lw[(c0+1)*2+1];
    #pragma unroll
    for (int o = 32; o >= 1; o >>= 1){ l0 += __shfl_xor(l0,o,64); l1 += __shfl_xor(l1,o,64); }
    if (lane == 0){
      l0 += lb[0]; l1 += lb[1];
      float m = fmaxf(l0,l1);
      float e0 = __expf(l0-m), e1 = __expf(l1-m);
      float si = e0 + e1;
      out[g*2]   = e0/si;
      out[g*2+1] = e1/si;
    }
  }
}

extern "C" void kernel_launch(void* const* d_in, const int* in_sizes, int n_in,
                              void* d_out, int out_size, void* d_ws, size_t ws_size,
                              hipStream_t stream){
  const float* x   = (const float*)d_in[0];
  const int*   ei  = (const int*)d_in[1];
  const int*   bat = (const int*)d_in[2];
  const float* W1  = (const float*)d_in[3];
  const float* a1s = (const float*)d_in[4];
  const float* a1d = (const float*)d_in[5];
  const float* b1  = (const float*)d_in[6];
  const float* W2  = (const float*)d_in[7];
  const float* a2s = (const float*)d_in[8];
  const float* a2d = (const float*)d_in[9];
  const float* b2  = (const float*)d_in[10];
  const float* lw  = (const float*)d_in[11];
  const float* lb  = (const float*)d_in[12];
  float* out = (float*)d_out;

  char* w = (char*)d_ws;
  auto alloc = [&](size_t bytes)->void*{ void* p = (void*)w; w += (bytes + 511) & ~size_t(511); return p; };
  int* offc   = (int*)alloc((size_t)(N_NODES+1)*4);
  int* cnt4   = (int*)alloc((size_t)CNT4_LEN*4);
  int* psum   = (int*)alloc((size_t)CNT4_LEN*4);
  int* bsum   = (int*)alloc((size_t)(NB_SCAN4+1)*4);
  int* csrc   = (int*)alloc((size_t)E_TOTAL*4);
  int* goff   = (int*)alloc((size_t)(N_GRAPHS+1)*4);
  int* gpos   = (int*)alloc((size_t)NBUK*4);
  unsigned* gbin = (unsigned*)alloc((size_t)NBUK*BCAP*4);
  unsigned short* w2t  = (unsigned short*)alloc((size_t)HC*HC*2);
  unsigned short* w1t  = (unsigned short*)alloc((size_t)HC*32*2);
  unsigned short* xbf  = (unsigned short*)alloc((size_t)N_NODES*32*2);
  unsigned short* hbf  = (unsigned short*)alloc((size_t)N_NODES*HC*2);
  unsigned short* hbf2 = (unsigned short*)alloc((size_t)N_NODES*HC*2);
  float* lsb  = (float*)alloc((size_t)N_NODES*HEADS*4);
  float* ldb  = (float*)alloc((size_t)N_NODES*HEADS*4);

  hipMemsetAsync(gpos, 0, (size_t)NBUK*4, stream);

  // K1: bin | goff | w2t | x->bf16 | w1t
  k_pre  <<<NBIN_BLK + GOFF_BLK + WCONV_BLK + XCONV_BLK + W1CONV_BLK,BIN_TPB,0,stream>>>(
           ei, gpos, gbin, bat, goff, W2, w2t, x, xbf, W1, w1t);
  // CSR finalize: private counts -> scan -> private scatter (no global atomics)
  k_cnt4 <<<NBUK*CSR_SPLIT,256,0,stream>>>(gpos, gbin, cnt4);
  k_scan1<<<NB_SCAN4,SCAN_B,0,stream>>>(cnt4, psum, bsum);
  k_scan2<<<1,512,0,stream>>>(bsum, NB_SCAN4);
  k_scan3<<<(CNT4_LEN+255)/256,256,0,stream>>>(psum, bsum, offc);
  // layer-1 GEMM via MFMA (+fused logits) — independent of scatter
  k_gemm_mfma<1><<<(N_NODES+63)/64,256,0,stream>>>(xbf, w1t, a1s, a1d, hbf, lsb, ldb);
  k_scat4<<<NBUK*CSR_SPLIT,256,0,stream>>>(gpos, gbin, psum, csrc);

  // layer 1 aggregation
  k_agg  <<<(N_NODES+3)/4,256,0,stream>>>(offc, csrc, hbf, lsb, ldb, b1, hbf2);
  // layer 2 (MFMA GEMM + fused logits)
  k_gemm_mfma<4><<<(N_NODES+63)/64,256,0,stream>>>(hbf2, w2t, a2s, a2d, hbf, lsb, ldb);
  k_agg  <<<(N_NODES+3)/4,256,0,stream>>>(offc, csrc, hbf, lsb, ldb, b2, hbf2);

  // pooling + classifier
  k_poolcls<<<N_GRAPHS,256,0,stream>>>(hbf2, goff, lw, lb, out);
}

// Round 17
// 266.840 us; speedup vs baseline: 1.3907x; 1.0773x over previous
//
#include <hip/hip_runtime.h>
#include <math.h>

#define N_NODES 100000
#define N_EDGESI 1600000
#define E_TOTAL (N_EDGESI + N_NODES)
#define N_GRAPHS 2000
#define F_IN 16
#define HEADS 8
#define CPH 16
#define HC 128
#define NEG 0.2f

// bucketed scatter params
#define BSHIFT 9
#define BNODES (1<<BSHIFT)                         // 512 nodes per bucket
#define NBUK ((N_NODES + BNODES - 1)/BNODES)       // 196
#define BCAP 12288
#define BIN_EPT 8
#define BIN_TPB 256
#define BIN_EPB (BIN_EPT*BIN_TPB)                  // 2048
#define NBIN_BLK ((E_TOTAL + BIN_EPB - 1)/BIN_EPB) // 831
#define CSR_EPT (BCAP/512)                         // 24 entries/thread max

#define GOFF_BLK ((N_NODES+255)/256)               // 391
#define WCONV_BLK ((HC*HC)/256)                    // 64
#define XCONV_BLK ((N_NODES*4 + 255)/256)          // 1563
#define W1CONV_BLK ((HC*32)/256)                   // 16

typedef __bf16 bf16x8 __attribute__((ext_vector_type(8)));
typedef float  f32x4  __attribute__((ext_vector_type(4)));

__device__ __forceinline__ float leaky(float x){ return fmaxf(x, NEG*x); }
__device__ __forceinline__ float bf2f(unsigned short u){ return __uint_as_float(((unsigned)u)<<16); }
__device__ __forceinline__ unsigned short f2bf(float f){
  unsigned u = __float_as_uint(f);
  unsigned r = (u + 0x7fffu + ((u>>16)&1u)) >> 16;
  return (unsigned short)r;
}
__device__ __forceinline__ float blo(unsigned u){ return __uint_as_float(u<<16); }
__device__ __forceinline__ float bhi(unsigned u){ return __uint_as_float(u & 0xffff0000u); }

// ---------- K1: bin (LDS counting sort) | goff | W2t | x->bf16 | W1t ----------
__global__ void k_pre(const int* __restrict__ ei, int* __restrict__ gpos, unsigned* __restrict__ gbin,
                      const int* __restrict__ batch, int* __restrict__ goff,
                      const float* __restrict__ W2, unsigned short* __restrict__ w2t,
                      const float* __restrict__ x, unsigned short* __restrict__ xbf,
                      const float* __restrict__ W1, unsigned short* __restrict__ w1t){
  int blk = blockIdx.x;
  if (blk < NBIN_BLK){
    __shared__ int cnt[NBUK];
    __shared__ int lofs[NBUK];
    __shared__ int bbase[NBUK];
    __shared__ int ws[4];
    __shared__ unsigned sorted[BIN_EPB];     // 8 KB
    __shared__ unsigned short sbkt[BIN_EPB]; // 4 KB
    int t = threadIdx.x;
    for (int i = t; i < NBUK; i += BIN_TPB) cnt[i] = 0;
    __syncthreads();
    int base = blk*BIN_EPB;
    unsigned entry[BIN_EPT]; int ebkt[BIN_EPT]; int erank[BIN_EPT];
    #pragma unroll
    for (int i = 0; i < BIN_EPT; ++i){
      int e = base + i*BIN_TPB + t;
      if (e < E_TOTAL){
        unsigned s, d;
        if (e < N_EDGESI){ s = (unsigned)ei[e]; d = (unsigned)ei[N_EDGESI + e]; }
        else { s = d = (unsigned)(e - N_EDGESI); }
        int b = (int)(d >> BSHIFT);
        erank[i] = atomicAdd(&cnt[b], 1);
        ebkt[i] = b;
        entry[i] = ((d & (BNODES-1u)) << 17) | s;
      } else ebkt[i] = -1;
    }
    __syncthreads();
    {
      int lane = t & 63, wv = t >> 6;
      int v = (t < NBUK) ? cnt[t] : 0;
      int sc = v;
      #pragma unroll
      for (int o = 1; o < 64; o <<= 1){ int u = __shfl_up(sc, o, 64); if (lane >= o) sc += u; }
      if (lane == 63) ws[wv] = sc;
      __syncthreads();
      if (wv == 0 && lane < 4){
        int w2v = ws[lane];
        #pragma unroll
        for (int o = 1; o < 4; o <<= 1){ int u = __shfl_up(w2v, o, 64); if (lane >= o) w2v += u; }
        ws[lane] = w2v;
      }
      __syncthreads();
      if (t < NBUK){
        lofs[t] = (wv ? ws[wv-1] : 0) + sc - v;
        bbase[t] = v ? atomicAdd(&gpos[t], v) : 0;
      }
    }
    __syncthreads();
    #pragma unroll
    for (int i = 0; i < BIN_EPT; ++i){
      if (ebkt[i] >= 0){
        int p = lofs[ebkt[i]] + erank[i];
        sorted[p] = entry[i];
        sbkt[p] = (unsigned short)ebkt[i];
      }
    }
    __syncthreads();
    int nval = E_TOTAL - base; if (nval > BIN_EPB) nval = BIN_EPB;
    for (int i = t; i < nval; i += BIN_TPB){
      int b = sbkt[i];
      gbin[(size_t)b*BCAP + bbase[b] + (i - lofs[b])] = sorted[i];
    }
  } else if (blk < NBIN_BLK + GOFF_BLK){
    int n = (blk - NBIN_BLK)*256 + threadIdx.x;
    if (n >= N_NODES) return;
    int b = batch[n];
    if (n == 0){ for (int g = 0; g <= b; ++g) goff[g] = 0; }
    int b1 = (n+1 < N_NODES) ? batch[n+1] : N_GRAPHS;
    for (int g = b+1; g <= b1; ++g) goff[g] = n+1;
  } else if (blk < NBIN_BLK + GOFF_BLK + WCONV_BLK){
    int i = (blk - NBIN_BLK - GOFF_BLK)*256 + threadIdx.x;  // c*128 + k
    if (i >= HC*HC) return;
    int c = i >> 7, k = i & 127;
    w2t[i] = f2bf(W2[k*HC + c]);
  } else if (blk < NBIN_BLK + GOFF_BLK + WCONV_BLK + XCONV_BLK){
    int p = (blk - NBIN_BLK - GOFF_BLK - WCONV_BLK)*256 + threadIdx.x;  // n*4 + quad
    if (p >= N_NODES*4) return;
    int n = p >> 2, q = p & 3;
    float4 xv = ((const float4*)(x + n*F_IN))[q];
    ushort4 o; o.x = f2bf(xv.x); o.y = f2bf(xv.y); o.z = f2bf(xv.z); o.w = f2bf(xv.w);
    ((ushort4*)(xbf + (size_t)n*32))[q] = o;
    ushort4 z; z.x = 0; z.y = 0; z.z = 0; z.w = 0;
    ((ushort4*)(xbf + (size_t)n*32 + 16))[q] = z;
  } else {
    int i = (blk - NBIN_BLK - GOFF_BLK - WCONV_BLK - XCONV_BLK)*256 + threadIdx.x;  // c*32+k
    if (i >= HC*32) return;
    int c = i >> 5, k = i & 31;
    w1t[i] = (k < F_IN) ? f2bf(W1[k*HC + c]) : (unsigned short)0;
  }
}

// ---------- fused CSR: single gbin read (register stash) + count + scan + scatter ----------
__global__ __launch_bounds__(512) void k_csr(
                      const int* __restrict__ gpos, const unsigned* __restrict__ gbin,
                      int* __restrict__ off, int* __restrict__ csrc){
  __shared__ int lcnt[BNODES];       // 2 KB
  __shared__ int wsum[8];
  __shared__ int gp[NBUK];
  __shared__ int sbase;
  int b = blockIdx.x, t = threadIdx.x;    // 512 threads
  for (int i = t; i < NBUK; i += 512) gp[i] = gpos[i];
  lcnt[t] = 0;
  __syncthreads();
  if (t == 0){ int s = 0; for (int j = 0; j < b; ++j) s += gp[j]; sbase = s; }
  int nb = gp[b];
  const unsigned* bb = gbin + (size_t)b*BCAP;
  // register stash: compile-time-indexed (no scratch)
  unsigned ent[CSR_EPT];
  #pragma unroll
  for (int j = 0; j < CSR_EPT; ++j){
    int i = j*512 + t;
    ent[j] = (i < nb) ? bb[i] : 0xffffffffu;   // valid entries have top bits 0 (<=26 bits)
  }
  __syncthreads();
  int base = sbase;
  #pragma unroll
  for (int j = 0; j < CSR_EPT; ++j)
    if (ent[j] != 0xffffffffu) atomicAdd(&lcnt[ent[j] >> 17], 1);
  __syncthreads();
  // block scan of 512 counters
  int lane = t & 63, wv = t >> 6;
  int v = lcnt[t];
  int sc = v;
  #pragma unroll
  for (int o = 1; o < 64; o <<= 1){ int u = __shfl_up(sc, o, 64); if (lane >= o) sc += u; }
  if (lane == 63) wsum[wv] = sc;
  __syncthreads();
  if (wv == 0 && lane < 8){
    int w2 = wsum[lane];
    #pragma unroll
    for (int o = 1; o < 8; o <<= 1){ int u = __shfl_up(w2, o, 64); if (lane >= o) w2 += u; }
    wsum[lane] = w2;
  }
  __syncthreads();
  int excl = (wv ? wsum[wv-1] : 0) + sc - v;
  int d = (b << BSHIFT) + t;
  if (d < N_NODES) off[d] = base + excl;
  if (b == NBUK-1 && t == 0) off[N_NODES] = E_TOTAL;
  __syncthreads();
  lcnt[t] = base + excl;    // global cursors
  __syncthreads();
  #pragma unroll
  for (int j = 0; j < CSR_EPT; ++j){
    if (ent[j] != 0xffffffffu){
      int p = atomicAdd(&lcnt[ent[j] >> 17], 1);
      csrc[p] = (int)(ent[j] & 0x1ffffu);
    }
  }
}

// ---------- GEMM via MFMA bf16 (both layers), fused logits via LDS stage ----------
template<int KS>
__global__ __launch_bounds__(256) void k_gemm_mfma(
                             const unsigned short* __restrict__ hin,
                             const unsigned short* __restrict__ wt,
                             const float* __restrict__ asrc, const float* __restrict__ adst,
                             unsigned short* __restrict__ hb,
                             float* __restrict__ ls, float* __restrict__ ld){
  __shared__ unsigned short hls[64][132];   // pad 132 -> conflict-free b64 reads
  const int KST = KS*32;
  int t = threadIdx.x, lane = t & 63, wv = t >> 6;
  int n0 = blockIdx.x*64 + wv*16;
  int rowl = lane & 15, kgrp = lane >> 4;
  int row = n0 + rowl;
  int rowc = (row < N_NODES) ? row : (N_NODES-1);
  bf16x8 a[KS];
  #pragma unroll
  for (int ks = 0; ks < KS; ++ks)
    a[ks] = *(const bf16x8*)(hin + (size_t)rowc*KST + ks*32 + kgrp*8);
  #pragma unroll
  for (int ct = 0; ct < 8; ++ct){
    f32x4 acc = {0.f, 0.f, 0.f, 0.f};
    int col = ct*16 + rowl;
    #pragma unroll
    for (int ks = 0; ks < KS; ++ks){
      bf16x8 b = *(const bf16x8*)(wt + (size_t)col*KST + ks*32 + kgrp*8);
      acc = __builtin_amdgcn_mfma_f32_16x16x32_bf16(a[ks], b, acc, 0, 0, 0);
    }
    #pragma unroll
    for (int r = 0; r < 4; ++r){
      int lrow = wv*16 + kgrp*4 + r;
      int ro = n0 + kgrp*4 + r;
      unsigned short hv = f2bf(acc[r]);
      hls[lrow][col] = hv;
      if (ro < N_NODES) hb[(size_t)ro*HC + col] = hv;
    }
  }
  __syncthreads();
  #pragma unroll
  for (int pp = 0; pp < 2; ++pp){
    int p = t + pp*256;
    int lrow = p >> 3, h = p & 7;
    int gn = blockIdx.x*64 + lrow;
    if (gn < N_NODES){
      const unsigned short* rp = &hls[lrow][h*16];
      uint2 A = *(const uint2*)rp;
      uint2 B = *(const uint2*)(rp+4);
      uint2 C = *(const uint2*)(rp+8);
      uint2 D = *(const uint2*)(rp+12);
      float c[16] = { blo(A.x), bhi(A.x), blo(A.y), bhi(A.y),
                      blo(B.x), bhi(B.x), blo(B.y), bhi(B.y),
                      blo(C.x), bhi(C.x), blo(C.y), bhi(C.y),
                      blo(D.x), bhi(D.x), blo(D.y), bhi(D.y) };
      const float* as = asrc + h*CPH;
      const float* ad = adst + h*CPH;
      float s0 = 0.f, s1 = 0.f;
      #pragma unroll
      for (int q = 0; q < 16; ++q){ s0 += c[q]*as[q]; s1 += c[q]*ad[q]; }
      ls[gn*8 + h] = s0;
      ld[gn*8 + h] = s1;
    }
  }
}

// ---------- attention + aggregation ----------
__global__ void k_agg(const int* __restrict__ off, const int* __restrict__ csrc,
                      const unsigned short* __restrict__ hb, const float* __restrict__ ls,
                      const float* __restrict__ ld, const float* __restrict__ bias,
                      unsigned short* __restrict__ outb){
  int wid = threadIdx.x >> 6, lane = threadIdx.x & 63;
  int n = blockIdx.x*4 + wid;
  if (n >= N_NODES) return;
  int rs = __builtin_amdgcn_readfirstlane(off[n]);
  int re = __builtin_amdgcn_readfirstlane(off[n+1]);
  int q = lane >> 4;               // quarter: which of 4 parallel edges
  int l = lane & 15;               // lane-in-quarter: channels l*8 .. l*8+7
  int h = l >> 1;                  // head of those channels
  float ldh = ld[n*8 + h];
  const uint4* hb4 = (const uint4*)hb;    // 16 uint4 per 256B row
  float ac0=0.f, ac1=0.f, ac2=0.f, ac3=0.f, ac4=0.f, ac5=0.f, ac6=0.f, ac7=0.f, dsum=0.f;
  #define AGG_BODY(J) { \
    int s = __shfl(sv, (J), 64); \
    float g = ls[s*8 + h]; \
    float ex = __expf(leaky(g + ldh)); \
    uint4 v = hb4[(size_t)s*16 + l]; \
    ac0 += ex*blo(v.x); ac1 += ex*bhi(v.x); \
    ac2 += ex*blo(v.y); ac3 += ex*bhi(v.y); \
    ac4 += ex*blo(v.z); ac5 += ex*bhi(v.z); \
    ac6 += ex*blo(v.w); ac7 += ex*bhi(v.w); \
    dsum += ex; }
  int nb = re - rs;
  for (int cb = 0; cb < nb; cb += 64){
    int cnt = nb - cb; if (cnt > 64) cnt = 64;
    int sv = csrc[rs + cb + (lane < cnt ? lane : 0)];   // one coalesced load / 64 edges
    int jj = 0;
    for (; jj + 16 <= cnt; jj += 16){
      AGG_BODY(jj+q) AGG_BODY(jj+q+4) AGG_BODY(jj+q+8) AGG_BODY(jj+q+12)
    }
    for (int j = jj + q; j < cnt; j += 4) AGG_BODY(j)
  }
  #undef AGG_BODY
  ac0 += __shfl_xor(ac0,16,64); ac0 += __shfl_xor(ac0,32,64);
  ac1 += __shfl_xor(ac1,16,64); ac1 += __shfl_xor(ac1,32,64);
  ac2 += __shfl_xor(ac2,16,64); ac2 += __shfl_xor(ac2,32,64);
  ac3 += __shfl_xor(ac3,16,64); ac3 += __shfl_xor(ac3,32,64);
  ac4 += __shfl_xor(ac4,16,64); ac4 += __shfl_xor(ac4,32,64);
  ac5 += __shfl_xor(ac5,16,64); ac5 += __shfl_xor(ac5,32,64);
  ac6 += __shfl_xor(ac6,16,64); ac6 += __shfl_xor(ac6,32,64);
  ac7 += __shfl_xor(ac7,16,64); ac7 += __shfl_xor(ac7,32,64);
  dsum += __shfl_xor(dsum,16,64); dsum += __shfl_xor(dsum,32,64);
  if (q == 0){
    float inv = 1.f/fmaxf(dsum, 1e-16f);
    float4 b0 = ((const float4*)bias)[l*2];
    float4 b1 = ((const float4*)bias)[l*2+1];
    uint4 o;
    o.x = (unsigned)f2bf(fmaxf(ac0*inv + b0.x, 0.f)) | ((unsigned)f2bf(fmaxf(ac1*inv + b0.y, 0.f)) << 16);
    o.y = (unsigned)f2bf(fmaxf(ac2*inv + b0.z, 0.f)) | ((unsigned)f2bf(fmaxf(ac3*inv + b0.w, 0.f)) << 16);
    o.z = (unsigned)f2bf(fmaxf(ac4*inv + b1.x, 0.f)) | ((unsigned)f2bf(fmaxf(ac5*inv + b1.y, 0.f)) << 16);
    o.w = (unsigned)f2bf(fmaxf(ac6*inv + b1.z, 0.f)) | ((unsigned)f2bf(fmaxf(ac7*inv + b1.w, 0.f)) << 16);
    ((uint4*)outb)[(size_t)n*16 + l] = o;
  }
}

// ---------- pooling + classify fused (bf16 input) ----------
__global__ void k_poolcls(const unsigned short* __restrict__ h, const int* __restrict__ goff,
                          const float* __restrict__ lw, const float* __restrict__ lb,
                          float* __restrict__ out){
  __shared__ float sh[4][HC];
  int g = blockIdx.x;
  int t = threadIdx.x, lane = t & 63, wv = t >> 6;
  int s = goff[g], epos = goff[g+1];
  float a0 = 0.f, a1 = 0.f;
  const ushort2* h2 = (const ushort2*)h;
  for (int n = s + wv; n < epos; n += 4){
    ushort2 v = h2[(size_t)n*64 + lane];
    a0 += bf2f(v.x); a1 += bf2f(v.y);
  }
  sh[wv][lane*2] = a0; sh[wv][lane*2+1] = a1;
  __syncthreads();
  if (wv == 0){
    int c0 = lane*2;
    float p0 = sh[0][c0] + sh[1][c0] + sh[2][c0] + sh[3][c0];
    float p1 = sh[0][c0+1] + sh[1][c0+1] + sh[2][c0+1] + sh[3][c0+1];
    int cntg = epos - s;
    float invc = 1.f/fmaxf((float)cntg, 1.f);
    float v0 = p0*invc, v1 = p1*invc;
    float l0 = v0*lw[c0*2+0] + v1*lw[(c0+1)*2+0];
    float l1 = v0*lw[c0*2+1] + v1*lw[(c0+1)*2+1];
    #pragma unroll
    for (int o = 32; o >= 1; o >>= 1){ l0 += __shfl_xor(l0,o,64); l1 += __shfl_xor(l1,o,64); }
    if (lane == 0){
      l0 += lb[0]; l1 += lb[1];
      float m = fmaxf(l0,l1);
      float e0 = __expf(l0-m), e1 = __expf(l1-m);
      float si = e0 + e1;
      out[g*2]   = e0/si;
      out[g*2+1] = e1/si;
    }
  }
}

extern "C" void kernel_launch(void* const* d_in, const int* in_sizes, int n_in,
                              void* d_out, int out_size, void* d_ws, size_t ws_size,
                              hipStream_t stream){
  const float* x   = (const float*)d_in[0];
  const int*   ei  = (const int*)d_in[1];
  const int*   bat = (const int*)d_in[2];
  const float* W1  = (const float*)d_in[3];
  const float* a1s = (const float*)d_in[4];
  const float* a1d = (const float*)d_in[5];
  const float* b1  = (const float*)d_in[6];
  const float* W2  = (const float*)d_in[7];
  const float* a2s = (const float*)d_in[8];
  const float* a2d = (const float*)d_in[9];
  const float* b2  = (const float*)d_in[10];
  const float* lw  = (const float*)d_in[11];
  const float* lb  = (const float*)d_in[12];
  float* out = (float*)d_out;

  char* w = (char*)d_ws;
  auto alloc = [&](size_t bytes)->void*{ void* p = (void*)w; w += (bytes + 511) & ~size_t(511); return p; };
  int* off    = (int*)alloc((size_t)(N_NODES+1)*4);
  int* csrc   = (int*)alloc((size_t)E_TOTAL*4);
  int* goff   = (int*)alloc((size_t)(N_GRAPHS+1)*4);
  int* gpos   = (int*)alloc((size_t)NBUK*4);
  unsigned* gbin = (unsigned*)alloc((size_t)NBUK*BCAP*4);
  unsigned short* w2t  = (unsigned short*)alloc((size_t)HC*HC*2);
  unsigned short* w1t  = (unsigned short*)alloc((size_t)HC*32*2);
  unsigned short* xbf  = (unsigned short*)alloc((size_t)N_NODES*32*2);
  unsigned short* hbf  = (unsigned short*)alloc((size_t)N_NODES*HC*2);
  unsigned short* hbf2 = (unsigned short*)alloc((size_t)N_NODES*HC*2);
  float* lsb  = (float*)alloc((size_t)N_NODES*HEADS*4);
  float* ldb  = (float*)alloc((size_t)N_NODES*HEADS*4);

  hipMemsetAsync(gpos, 0, (size_t)NBUK*4, stream);

  // K1: bin | goff | w2t | x->bf16 | w1t
  k_pre  <<<NBIN_BLK + GOFF_BLK + WCONV_BLK + XCONV_BLK + W1CONV_BLK,BIN_TPB,0,stream>>>(
           ei, gpos, gbin, bat, goff, W2, w2t, x, xbf, W1, w1t);
  // layer-1 GEMM via MFMA (+fused logits)
  k_gemm_mfma<1><<<(N_NODES+63)/64,256,0,stream>>>(xbf, w1t, a1s, a1d, hbf, lsb, ldb);
  // CSR build (single gbin read)
  k_csr  <<<NBUK,512,0,stream>>>(gpos, gbin, off, csrc);

  // layer 1 aggregation
  k_agg  <<<(N_NODES+3)/4,256,0,stream>>>(off, csrc, hbf, lsb, ldb, b1, hbf2);
  // layer 2 (MFMA GEMM + fused logits)
  k_gemm_mfma<4><<<(N_NODES+63)/64,256,0,stream>>>(hbf2, w2t, a2s, a2d, hbf, lsb, ldb);
  k_agg  <<<(N_NODES+3)/4,256,0,stream>>>(off, csrc, hbf, lsb, ldb, b2, hbf2);

  // pooling + classifier
  k_poolcls<<<N_GRAPHS,256,0,stream>>>(hbf2, goff, lw, lb, out);
}